// Round 4
// baseline (399.333 us; speedup 1.0000x reference)
//
#include <hip/hip_runtime.h>
#include <math.h>

// Problem constants
#define BN 16
#define BC 256
#define BK 8
#define BM 63
#define MO 56
#define PLANE (BM * BM)            // 3969
#define S 68                        // LDS row stride in floats (16B multiple)

// 1-wave blocks: lane = ly*8 + lx ; per-lane output tile 7 rows x 8 cols.
// ly in 0..7 -> row0 = 7*ly (rows 0..55); lx in 0..6 -> col0 = 8*lx (cols 0..55).
// lx==7 lanes duplicate lx==6 (same LDS addrs -> broadcast), stores skipped.
#define T_CH 2
#define NCHUNK (BC / T_CH)          // 128 -> grid 16x128 = 2048 blocks = 8 waves/CU
#define NT 64

__global__ __launch_bounds__(NT, 2)
void bhat_kernel(const float* __restrict__ z,
                 const float* __restrict__ x,
                 const float* __restrict__ w,
                 float* __restrict__ out)
{
    __shared__ __align__(16) float xs[BM * S];   // 63*68*4 = 17136 B

    const int n    = blockIdx.x;
    const int ch0  = blockIdx.y * T_CH;
    const int lane = threadIdx.x;                // 0..63
    const int ly   = lane >> 3;                  // 0..7
    const int lxr  = lane & 7;                   // 0..7
    const int lx   = (lxr < 7) ? lxr : 6;        // clamp: lane dup -> LDS broadcast
    const int row0 = ly * 7;
    const int col0 = lx * 8;

    float acc[7][8];
#pragma unroll
    for (int a = 0; a < 7; ++a)
#pragma unroll
        for (int b = 0; b < 8; ++b) acc[a][b] = 0.0f;

#pragma unroll 1
    for (int ci = 0; ci < T_CH; ++ci) {
        const int c = ch0 + ci;
        const float* __restrict__ xp = x + (size_t)(n * BC + c) * PLANE;

        __syncthreads();  // single-wave: just orders LDS (prev readers done)
        // Stage sqrt(x) plane; 3969 = 62*64 + 1.
#pragma unroll
        for (int j = 0; j < 62; ++j) {
            int i = lane + NT * j;
            unsigned r  = (unsigned)i / 63u;
            unsigned cc = (unsigned)i - r * 63u;
            xs[r * S + cc] = sqrtf(xp[i]);
        }
        if (lane == 0) xs[62 * S + 62] = sqrtf(xp[3968]);
        __syncthreads();

        const float wsc = w[c] * (1.0f / 64.0f);
        const float* __restrict__ zp = z + (size_t)(n * BC + c) * 64;

#pragma unroll 1
        for (int p2 = 0; p2 < 4; ++p2) {
            const int p = 2 * p2;
            // z rows p, p+1 (16 floats), wave-uniform loads
            float4 za = *(const float4*)(zp + p * 8);
            float4 zb = *(const float4*)(zp + p * 8 + 4);
            float4 zc = *(const float4*)(zp + p * 8 + 8);
            float4 zd = *(const float4*)(zp + p * 8 + 12);
            float zr[2][8];
            zr[0][0] = sqrtf(za.x) * wsc;  zr[0][1] = sqrtf(za.y) * wsc;
            zr[0][2] = sqrtf(za.z) * wsc;  zr[0][3] = sqrtf(za.w) * wsc;
            zr[0][4] = sqrtf(zb.x) * wsc;  zr[0][5] = sqrtf(zb.y) * wsc;
            zr[0][6] = sqrtf(zb.z) * wsc;  zr[0][7] = sqrtf(zb.w) * wsc;
            zr[1][0] = sqrtf(zc.x) * wsc;  zr[1][1] = sqrtf(zc.y) * wsc;
            zr[1][2] = sqrtf(zc.z) * wsc;  zr[1][3] = sqrtf(zc.w) * wsc;
            zr[1][4] = sqrtf(zd.x) * wsc;  zr[1][5] = sqrtf(zd.y) * wsc;
            zr[1][6] = sqrtf(zd.z) * wsc;  zr[1][7] = sqrtf(zd.w) * wsc;

            const float* xb = &xs[(row0 + p) * S + col0];
#pragma unroll
            for (int rr = 0; rr < 8; ++rr) {
                // window row row0+p+rr: 16 floats [col0, col0+16) as 4 aligned b128
                const float4* x4 = (const float4*)(xb + rr * S);
                float4 a0 = x4[0], a1 = x4[1], a2 = x4[2], a3 = x4[3];
                float xv[16] = { a0.x, a0.y, a0.z, a0.w,
                                 a1.x, a1.y, a1.z, a1.w,
                                 a2.x, a2.y, a2.z, a2.w,
                                 a3.x, a3.y, a3.z, a3.w };
#pragma unroll
                for (int pp = 0; pp < 2; ++pp) {
                    if (rr == 0 && pp == 1) continue;   // a = -1
                    if (rr == 7 && pp == 0) continue;   // a = 7
                    const int a = rr - pp;              // 0..6
#pragma unroll
                    for (int q = 0; q < 8; ++q) {
                        const float zv = zr[pp][q];
#pragma unroll
                        for (int b = 0; b < 8; ++b)
                            acc[a][b] = fmaf(xv[q + b], zv, acc[a][b]);
                    }
                }
            }
        }
    }

    if (lxr < 7) {
        float* __restrict__ op = out + (size_t)n * (MO * MO);
#pragma unroll
        for (int a = 0; a < 7; ++a)
#pragma unroll
            for (int b = 0; b < 8; ++b)
                atomicAdd(op + (row0 + a) * MO + col0 + b, acc[a][b]);
    }
}

extern "C" void kernel_launch(void* const* d_in, const int* in_sizes, int n_in,
                              void* d_out, int out_size, void* d_ws, size_t ws_size,
                              hipStream_t stream) {
    const float* z = (const float*)d_in[0];   // (16,256,8,8)
    const float* x = (const float*)d_in[1];   // (16,256,63,63)
    const float* w = (const float*)d_in[2];   // (256)
    float* out = (float*)d_out;               // (16,1,56,56)

    (void)hipMemsetAsync(out, 0, (size_t)out_size * sizeof(float), stream);

    dim3 grid(BN, NCHUNK);
    bhat_kernel<<<grid, NT, 0, stream>>>(z, x, w, out);
}

// Round 5
// 197.395 us; speedup vs baseline: 2.0230x; 2.0230x over previous
//
#include <hip/hip_runtime.h>
#include <math.h>

#define BN 16
#define BC 256
#define BK 8
#define BM 63
#define MO 56
#define PLANE (BM * BM)       // 3969
#define SH 72                 // LDS row stride in halves (16B multiple)
#define SLICE (BM * SH)       // 4536 halves = 9072 B per wave's plane
#define WPB 4                 // waves per block; each wave owns one channel
#define NT (64 * WPB)         // 256 threads
#define NCHUNK (BC / WPB)     // 64 -> grid 16x64 = 1024 blocks x 4 waves = 16 waves/CU

typedef _Float16 half_t;
typedef __attribute__((ext_vector_type(8))) _Float16 half8;

__global__ __launch_bounds__(NT, 4)
void bhat_kernel(const float* __restrict__ z,
                 const float* __restrict__ x,
                 const float* __restrict__ w,
                 float* __restrict__ out)
{
    __shared__ __align__(16) char smem[WPB * SLICE * 2];   // 36288 B

    const int n    = blockIdx.x;
    const int wv   = threadIdx.x >> 6;
    const int lane = threadIdx.x & 63;
    const int c    = blockIdx.y * WPB + wv;     // this wave's channel
    const int ly   = lane >> 3;                 // 0..7
    const int lxr  = lane & 7;                  // 0..7
    const int lx   = (lxr < 7) ? lxr : 6;       // dup lane -> LDS broadcast
    const int row0 = ly * 7;                    // 0..49
    const int col0 = lx * 8;                    // 0..48 (16B aligned)
    half_t* xsh = (half_t*)smem + wv * SLICE;

    // ---- stage sqrt(x[n,c]) as f16 into this wave's private LDS slice ----
    const float* __restrict__ xp = x + (size_t)(n * BC + c) * PLANE;
    for (int j = 0; j < 62; ++j) {              // 62*64 = 3968
        int i = lane + 64 * j;
        int r  = (int)((unsigned)i / 63u);
        int cc = i - r * 63;
        xsh[r * SH + cc] = (half_t)sqrtf(xp[i]);
    }
    if (lane == 0) xsh[62 * SH + 62] = (half_t)sqrtf(xp[3968]);

    // ---- z row (wave-uniform) -> SGPR-resident via readlane ----
    const float wsc = w[c] * (1.0f / 64.0f);    // fold 1/k^2 + weight
    float vz  = sqrtf(z[(size_t)(n * BC + c) * 64 + lane]) * wsc;
    int   vzi = __float_as_int(vz);
    float sz[64];
#pragma unroll
    for (int k = 0; k < 64; ++k)
        sz[k] = __int_as_float(__builtin_amdgcn_readlane(vzi, k));

    float acc[7][8];
#pragma unroll
    for (int a = 0; a < 7; ++a)
#pragma unroll
        for (int b = 0; b < 8; ++b) acc[a][b] = 0.0f;

    // ---- main loop: each of the 14 window rows is read exactly ONCE ----
    // (same-wave LDS RAW: compiler's lgkmcnt ordering suffices; no barrier)
#pragma unroll
    for (int r = 0; r < 14; ++r) {
        const half_t* rp = xsh + (row0 + r) * SH + col0;
        half8 h0 = *(const half8*)rp;          // halves [col0, col0+8)
        half8 h1 = *(const half8*)(rp + 8);    // halves [col0+8, col0+16)
        float xv[15];
#pragma unroll
        for (int i = 0; i < 8; ++i) xv[i] = (float)h0[i];
#pragma unroll
        for (int i = 0; i < 7; ++i) xv[8 + i] = (float)h1[i];

#pragma unroll
        for (int a = 0; a < 7; ++a) {
            const int p = r - a;               // kernel row using this window row
            if (p < 0 || p > 7) continue;      // compile-time pruned
#pragma unroll
            for (int q = 0; q < 8; ++q) {
                const float zv = sz[8 * p + q];  // SGPR operand
#pragma unroll
                for (int b = 0; b < 8; ++b)
                    acc[a][b] = fmaf(xv[q + b], zv, acc[a][b]);
            }
        }
    }

    // ---- in-block reduction across the 4 waves (channels) ----
    __syncthreads();                            // all waves done reading x
    float* red = (float*)smem;                  // 3136 f32 aliases x region
    for (int i = threadIdx.x; i < MO * MO; i += NT) red[i] = 0.0f;
    __syncthreads();

    if (lxr < 7) {
#pragma unroll
        for (int a = 0; a < 7; ++a)
#pragma unroll
            for (int b = 0; b < 8; ++b)
                unsafeAtomicAdd(&red[(row0 + a) * MO + col0 + b], acc[a][b]);
    }
    __syncthreads();

    // ---- one HW-atomic pass to global (64 contenders per address) ----
    float* __restrict__ op = out + (size_t)n * (MO * MO);
    for (int i = threadIdx.x; i < MO * MO; i += NT)
        unsafeAtomicAdd(op + i, red[i]);
}

extern "C" void kernel_launch(void* const* d_in, const int* in_sizes, int n_in,
                              void* d_out, int out_size, void* d_ws, size_t ws_size,
                              hipStream_t stream) {
    const float* z = (const float*)d_in[0];   // (16,256,8,8)
    const float* x = (const float*)d_in[1];   // (16,256,63,63)
    const float* w = (const float*)d_in[2];   // (256)
    float* out = (float*)d_out;               // (16,1,56,56)

    (void)hipMemsetAsync(out, 0, (size_t)out_size * sizeof(float), stream);

    dim3 grid(BN, NCHUNK);
    bhat_kernel<<<grid, NT, 0, stream>>>(z, x, w, out);
}